// Round 1
// baseline (322.732 us; speedup 1.0000x reference)
//
#include <hip/hip_runtime.h>
#include <hip/hip_bf16.h>
#include <stdint.h>

// Problem constants
#define Bn 16
#define Ln 4096
#define KF 384   // IN_F
#define OF 384   // OUT_F

// GEMM tiling
#define BM 128
#define BN 128
#define BK 64
#define LDX 72   // padded leading dim (elements) for transposed X tile

static constexpr float kScale = 0.051031036307982884f;  // 1/sqrt(384)

typedef __attribute__((ext_vector_type(4))) float f32x4;
typedef __attribute__((ext_vector_type(2))) float f32x2;
typedef __attribute__((ext_vector_type(8))) short short8;   // 8 bf16 (4 VGPR) MFMA A/B frag
typedef __attribute__((ext_vector_type(4))) float floatx4;  // MFMA C/D frag
typedef __attribute__((ext_vector_type(4))) unsigned int uint4v;

__device__ __forceinline__ void gl_lds16(const void* g, void* l) {
  __builtin_amdgcn_global_load_lds(
      (const __attribute__((address_space(1))) unsigned int*)g,
      (__attribute__((address_space(3))) unsigned int*)l, 16, 0, 0);
}

// float -> bf16 bits, round-to-nearest-even (finite inputs only)
__device__ __forceinline__ unsigned int f2bf_bits(float f) {
  union { float f; unsigned int u; } v;
  v.f = f;
  return (v.u + 0x7FFFu + ((v.u >> 16) & 1u)) >> 16;
}
__device__ __forceinline__ unsigned int pack2bf(float lo, float hi) {
  return f2bf_bits(lo) | (f2bf_bits(hi) << 16);
}

// Kernel 1: wmod[b][o][k] = bf16( SCALE*weight[o][k]*y[b][k] * rsqrt(sum_k(.)^2 + eps) )
__global__ __launch_bounds__(256) void modw_kernel(const float* __restrict__ weight,
                                                   const float* __restrict__ y,
                                                   unsigned short* __restrict__ wmod) {
  int t = threadIdx.x;
  int wv = t >> 6, lane = t & 63;
  int row = blockIdx.x * 4 + wv;  // [0, Bn*OF)
  int b = row / OF, o = row % OF;
  const float* wr = weight + o * KF;
  const float* yr = y + b * KF;
  float vals[6];
  float ss = 0.f;
#pragma unroll
  for (int j = 0; j < 3; ++j) {
    int k = (lane + 64 * j) * 2;
    f32x2 wvv = *(const f32x2*)(wr + k);
    f32x2 yv = *(const f32x2*)(yr + k);
    float t0 = kScale * wvv[0] * yv[0];
    float t1 = kScale * wvv[1] * yv[1];
    vals[2 * j] = t0;
    vals[2 * j + 1] = t1;
    ss += t0 * t0 + t1 * t1;
  }
#pragma unroll
  for (int off = 32; off >= 1; off >>= 1) ss += __shfl_xor(ss, off, 64);
  float d = rsqrtf(ss + 1e-8f);
  unsigned short* orow = wmod + row * KF;
#pragma unroll
  for (int j = 0; j < 3; ++j) {
    int k = (lane + 64 * j) * 2;
    *(unsigned int*)(orow + k) = pack2bf(vals[2 * j] * d, vals[2 * j + 1] * d);
  }
}

// Kernel 2: per batch b: out[o][p] = sum_k wmod[b][o][k] * X[b][k][p]
// Occupancy-first variant: SINGLE-buffered sA (34 KB LDS total) -> 4 blocks/CU
// (16 waves/CU) for cross-block latency hiding. A DMA for chunk k+1 is issued
// between the two staging barriers (A is L2-resident; exposure ~200-400 cyc,
// hidden by the other 3 resident blocks). X prefetch-to-VGPR + convert still
// overlaps the MFMA section. Bank-conflict-free LDS via k-chunk XOR swizzles.
__global__ __launch_bounds__(256, 4) void gemm_kernel(const float* __restrict__ X,
                                                      const unsigned short* __restrict__ Wm,
                                                      float* __restrict__ out) {
  __shared__ unsigned short sA[BM * BK];  // [o][k-chunk swizzled by o&7], 16 KB
  __shared__ unsigned short sX[BN * LDX]; // [p][k-chunk swizzled], 18 KB

  // XCD swizzle: 3 consecutive logical blocks (sharing an X tile) -> same XCD
  int flat = blockIdx.x;                         // 0..1535
  int logical = (flat & 7) * 192 + (flat >> 3);  // bijection
  int mt = logical % 3;
  int nt = (logical / 3) & 31;
  int b = logical / 96;

  int t = threadIdx.x;
  int wave = t >> 6, lane = t & 63;
  int quad = lane >> 4;

  const float* Xb = X + b * (KF * Ln);
  const unsigned short* Wb = Wm + (b * OF + mt * BM) * KF;
  int pbase = nt * BN;

  floatx4 acc[4][4] = {};

  int i31 = t & 31;
  int p0 = i31 * 4;          // X staging: this thread's 4 columns
  int kr0 = (t >> 5) * 8;    // and 8 k-rows (natural)
  int kr0s = (((t >> 5) ^ (i31 & 7)) * 8);  // swizzled LDS k-offset for writes
  int arow = (wave >> 1) * 64 + (lane & 15);
  int brow = (wave & 1) * 64 + (lane & 15);
  int asw = lane & 7;                       // sA read swizzle
  int xsw = ((lane & 15) >> 2);             // sX read swizzle base (m4)

  // A staging: per-(wave,j) LDS dest is base + lane*16; source k-chunk is
  // XOR-permuted so that LDS chunk c' holds global chunk c'^(row&7).
  int aoff[4], asrc_row[4], asrc_c[4];
#pragma unroll
  for (int j = 0; j < 4; ++j) {
    int boff = wave * 4096 + j * 1024 + lane * 16;  // byte offset in 16KB tile
    int row = boff >> 7;                            // 128B per row (64 bf16)
    int cp = (boff >> 4) & 7;                       // LDS chunk slot
    aoff[j] = boff;
    asrc_row[j] = row;
    asrc_c[j] = (cp ^ (row & 7)) * 8;               // global k-element offset
  }

  f32x4 xv[8];
  unsigned int wv4[4][4];

  // ---- prologue: stage A(0) via DMA, load+convert+write X(0) ----
#pragma unroll
  for (int j = 0; j < 4; ++j)
    gl_lds16(Wb + asrc_row[j] * KF + 0 + asrc_c[j], (char*)sA + aoff[j]);
  {
    const float* xsrc = Xb + (0 + kr0) * Ln + pbase + p0;
#pragma unroll
    for (int i = 0; i < 8; ++i) xv[i] = *(const f32x4*)(xsrc + i * Ln);
#pragma unroll
    for (int j = 0; j < 4; ++j)
#pragma unroll
      for (int i = 0; i < 4; ++i)
        wv4[j][i] = pack2bf(xv[2 * i][j], xv[2 * i + 1][j]);
#pragma unroll
    for (int j = 0; j < 4; ++j)
      *(uint4v*)(&sX[(p0 + j) * LDX + kr0s]) = *(uint4v*)wv4[j];
  }
  __syncthreads();  // drains A DMA (vmcnt) + publishes sX

#pragma unroll
  for (int kc = 0; kc < 6; ++kc) {
    // ---- prefetch next X chunk to VGPRs (latency hides under MFMA) ----
    if (kc < 5) {
      int k0n = (kc + 1) * BK;
      const float* xsrc = Xb + (k0n + kr0) * Ln + pbase + p0;
#pragma unroll
      for (int i = 0; i < 8; ++i) xv[i] = *(const f32x4*)(xsrc + i * Ln);
    }
    // ---- MFMA on current chunk ----
#pragma unroll
    for (int s = 0; s < 2; ++s) {
      short8 af[4], bf[4];
#pragma unroll
      for (int mi = 0; mi < 4; ++mi) {
        int ca = (((s << 2) | quad) ^ asw) * 8;
        af[mi] = *(const short8*)(&sA[(arow + mi * 16) * BK + ca]);
      }
#pragma unroll
      for (int ni = 0; ni < 4; ++ni) {
        int cx = (((s << 2) | quad) ^ (((ni & 1) << 2) | xsw)) * 8;
        bf[ni] = *(const short8*)(&sX[(brow + ni * 16) * LDX + cx]);
      }
      __builtin_amdgcn_s_setprio(1);
#pragma unroll
      for (int mi = 0; mi < 4; ++mi)
#pragma unroll
        for (int ni = 0; ni < 4; ++ni)
          acc[mi][ni] = __builtin_amdgcn_mfma_f32_16x16x32_bf16(af[mi], bf[ni], acc[mi][ni], 0, 0, 0);
      __builtin_amdgcn_s_setprio(0);
    }
    // ---- staging phase: convert in shadow, barrier, DMA A(next)+publish sX ----
    if (kc < 5) {
      int k0n = (kc + 1) * BK;
#pragma unroll
      for (int j = 0; j < 4; ++j)
#pragma unroll
        for (int i = 0; i < 4; ++i)
          wv4[j][i] = pack2bf(xv[2 * i][j], xv[2 * i + 1][j]);
      __syncthreads();  // all waves done reading sA(kc) and sX(kc)
#pragma unroll
      for (int j = 0; j < 4; ++j)
        gl_lds16(Wb + asrc_row[j] * KF + k0n + asrc_c[j], (char*)sA + aoff[j]);
#pragma unroll
      for (int j = 0; j < 4; ++j)
        *(uint4v*)(&sX[(p0 + j) * LDX + kr0s]) = *(uint4v*)wv4[j];
      __syncthreads();  // publishes sX(kc+1), drains A(kc+1) DMA
    }
  }

  // --- epilogue: C/D layout col=lane&15, row=quad*4+r ---
  float* outb = out + (b * OF + mt * BM) * Ln + pbase;
  int col = lane & 15;
#pragma unroll
  for (int mi = 0; mi < 4; ++mi) {
    int ob = (wave >> 1) * 64 + mi * 16 + quad * 4;
#pragma unroll
    for (int ni = 0; ni < 4; ++ni) {
      int p = (wave & 1) * 64 + ni * 16 + col;
#pragma unroll
      for (int r = 0; r < 4; ++r) outb[(ob + r) * Ln + p] = acc[mi][ni][r];
    }
  }
}

extern "C" void kernel_launch(void* const* d_in, const int* in_sizes, int n_in,
                              void* d_out, int out_size, void* d_ws, size_t ws_size,
                              hipStream_t stream) {
  const float* Efou = (const float*)d_in[0];    // [B, L, IN_F] fp32
  const float* y = (const float*)d_in[1];       // [B, IN_F] fp32
  const float* weight = (const float*)d_in[2];  // [1, OUT_F, IN_F] fp32
  float* out = (float*)d_out;                   // [B*OUT_F*L] fp32 (flat)
  unsigned short* wmod = (unsigned short*)d_ws; // [B, OUT_F, IN_F] bf16, 4.7MB

  modw_kernel<<<(Bn * OF) / 4, 256, 0, stream>>>(weight, y, wmod);
  gemm_kernel<<<Bn * (OF / BM) * (Ln / BN), 256, 0, stream>>>(Efou, wmod, out);
}

// Round 2
// 217.936 us; speedup vs baseline: 1.4809x; 1.4809x over previous
//
#include <hip/hip_runtime.h>
#include <hip/hip_bf16.h>
#include <stdint.h>

// Problem constants
#define Bn 16
#define Ln 4096
#define KF 384   // IN_F
#define OF 384   // OUT_F

// GEMM tiling (DMA path)
#define BM 128
#define BN 128
#define BK2 32
#define NKC (KF / BK2)  // 12

// Fallback GEMM tiling (round-0 path)
#define BK 64
#define LDX 72

static constexpr float kScale = 0.051031036307982884f;  // 1/sqrt(384)

typedef __attribute__((ext_vector_type(4))) float f32x4;
typedef __attribute__((ext_vector_type(2))) float f32x2;
typedef __attribute__((ext_vector_type(8))) short short8;   // 8 bf16 (4 VGPR) MFMA A/B frag
typedef __attribute__((ext_vector_type(4))) float floatx4;  // MFMA C/D frag
typedef __attribute__((ext_vector_type(4))) unsigned int uint4v;

__device__ __forceinline__ void gl_lds16(const void* g, void* l) {
  __builtin_amdgcn_global_load_lds(
      (const __attribute__((address_space(1))) unsigned int*)g,
      (__attribute__((address_space(3))) unsigned int*)l, 16, 0, 0);
}

// float -> bf16 bits, round-to-nearest-even (finite inputs only)
__device__ __forceinline__ unsigned int f2bf_bits(float f) {
  union { float f; unsigned int u; } v;
  v.f = f;
  return (v.u + 0x7FFFu + ((v.u >> 16) & 1u)) >> 16;
}
__device__ __forceinline__ unsigned int pack2bf(float lo, float hi) {
  return f2bf_bits(lo) | (f2bf_bits(hi) << 16);
}

// Kernel 1: wmod[b][o][k] = bf16( SCALE*weight[o][k]*y[b][k] * rsqrt(sum_k(.)^2 + eps) )
__global__ __launch_bounds__(256) void modw_kernel(const float* __restrict__ weight,
                                                   const float* __restrict__ y,
                                                   unsigned short* __restrict__ wmod) {
  int t = threadIdx.x;
  int wv = t >> 6, lane = t & 63;
  int row = blockIdx.x * 4 + wv;  // [0, Bn*OF)
  int b = row / OF, o = row % OF;
  const float* wr = weight + o * KF;
  const float* yr = y + b * KF;
  float vals[6];
  float ss = 0.f;
#pragma unroll
  for (int j = 0; j < 3; ++j) {
    int k = (lane + 64 * j) * 2;
    f32x2 wvv = *(const f32x2*)(wr + k);
    f32x2 yv = *(const f32x2*)(yr + k);
    float t0 = kScale * wvv[0] * yv[0];
    float t1 = kScale * wvv[1] * yv[1];
    vals[2 * j] = t0;
    vals[2 * j + 1] = t1;
    ss += t0 * t0 + t1 * t1;
  }
#pragma unroll
  for (int off = 32; off >= 1; off >>= 1) ss += __shfl_xor(ss, off, 64);
  float d = rsqrtf(ss + 1e-8f);
  unsigned short* orow = wmod + row * KF;
#pragma unroll
  for (int j = 0; j < 3; ++j) {
    int k = (lane + 64 * j) * 2;
    *(unsigned int*)(orow + k) = pack2bf(vals[2 * j] * d, vals[2 * j + 1] * d);
  }
}

// Kernel 1b: transpose-convert X fp32 [b][k=384][p=4096] -> Xbf bf16
// layout [b][kc=12][p=4096][k'=32], i.e. per 32-k panel, p-major with 32
// contiguous k per p (64B). This is exactly the linear LDS image the GEMM
// DMA-fills, so gemm_dma needs no VGPR staging and no converts.
// Reads: 64 lanes x 4B consecutive p = 256B coalesced per instruction.
// Writes: 16B per lane at 64B stride; 4 c-stores fill lines (L2 combines).
__global__ __launch_bounds__(256) void xpose_kernel(const float* __restrict__ X,
                                                    unsigned short* __restrict__ Xbf) {
  int t = threadIdx.x;
  int w = t >> 6, lane = t & 63;
  int wid = blockIdx.x * 4 + w;    // 0..12287 = (b*12+kc)*64 + pg
  int p = (wid & 63) * 64 + lane;  // 0..4095
  int bk = wid >> 6;               // 0..191 = b*12+kc
  int b = bk / NKC, kc = bk % NKC;
  const float* src = X + ((size_t)(b * KF + kc * BK2)) * Ln + p;
  unsigned short* dst = Xbf + ((size_t)bk * Ln + p) * BK2;
#pragma unroll
  for (int c = 0; c < 4; ++c) {
    float v[8];
#pragma unroll
    for (int e = 0; e < 8; ++e) v[e] = src[(size_t)(c * 8 + e) * Ln];
    unsigned int r[4];
#pragma unroll
    for (int i = 0; i < 4; ++i) r[i] = pack2bf(v[2 * i], v[2 * i + 1]);
    *(uint4v*)(dst + c * 8) = *(uint4v*)r;
  }
}

// Kernel 2 (DMA path): out[b][o][p] = sum_k wmod[b][o][k] * X[b][k][p]
// BK=32, both tiles double-buffered (32 KB LDS total), ALL staging via
// global_load_lds (no VGPR round-trip, no converts -> ~48 fewer VGPRs than
// round-0, fits 4 waves/SIMD budget without spill). ONE barrier per chunk:
// { issue DMA(kc+1 -> buf^1); ds_read frags from buf; 16 MFMA; barrier }.
// Natural [row][32] bf16 tiles are bank-conflict-free: byte addr =
// row*64 + quad*16 -> bank group = (row&1)*4 + quad, uniform 8 lanes/group.
__global__ __launch_bounds__(256, 4) void gemm_dma(const unsigned short* __restrict__ Xbf,
                                                   const unsigned short* __restrict__ Wm,
                                                   float* __restrict__ out) {
  __shared__ unsigned short sA[2][BM * BK2];  // [o][k] natural, 8KB each
  __shared__ unsigned short sX[2][BN * BK2];  // [p][k] natural, 8KB each

  // XCD swizzle: 3 consecutive logical blocks (sharing an X panel) -> same XCD
  int flat = blockIdx.x;                         // 0..1535
  int logical = (flat & 7) * 192 + (flat >> 3);  // bijection
  int mt = logical % 3;
  int nt = (logical / 3) & 31;
  int b = logical / 96;

  int t = threadIdx.x;
  int wave = t >> 6, lane = t & 63;
  int quad = lane >> 4;

  const unsigned short* Wb = Wm + (b * OF + mt * BM) * KF;
  int pbase = nt * BN;

  floatx4 acc[4][4] = {};

  int arow = (wave >> 1) * 64 + (lane & 15);
  int brow = (wave & 1) * 64 + (lane & 15);

  // DMA geometry: per wave 2 calls of 1KB each per tile.
  // LDS offset o = wave*2048 + j*1024 + lane*16 -> row = o>>6, kslot = lane&3.
  int drow = wave * 32 + (lane >> 2);
  int coff = (lane & 3) * 8;
  const unsigned short* asrc = Wb + drow * KF + coff;  // + kc*32 + j*16*KF
  const unsigned short* xsrc = Xbf + ((size_t)(b * NKC) * Ln + pbase + drow) * BK2 + coff;
  int ldsoff = wave * 2048 + lane * 16;

  // ---- prologue: DMA chunk 0 into buffer 0 ----
#pragma unroll
  for (int j = 0; j < 2; ++j) {
    gl_lds16(asrc + j * 16 * KF, (char*)sA[0] + ldsoff + j * 1024);
    gl_lds16(xsrc + j * 16 * BK2, (char*)sX[0] + ldsoff + j * 1024);
  }
  __syncthreads();  // drains DMA(0)

#pragma unroll
  for (int kc = 0; kc < NKC; ++kc) {
    int buf = kc & 1;
    // ---- issue DMA for next chunk into the other buffer ----
    if (kc < NKC - 1) {
#pragma unroll
      for (int j = 0; j < 2; ++j) {
        gl_lds16(asrc + j * 16 * KF + (kc + 1) * BK2, (char*)sA[buf ^ 1] + ldsoff + j * 1024);
        gl_lds16(xsrc + (size_t)(kc + 1) * Ln * BK2 + j * 16 * BK2,
                 (char*)sX[buf ^ 1] + ldsoff + j * 1024);
      }
    }
    // ---- MFMA on current chunk (k = kc*32 + quad*8 + e, same mapping as proven kernel) ----
    short8 af[4], bf[4];
#pragma unroll
    for (int mi = 0; mi < 4; ++mi)
      af[mi] = *(const short8*)(&sA[buf][(arow + mi * 16) * BK2 + quad * 8]);
#pragma unroll
    for (int ni = 0; ni < 4; ++ni)
      bf[ni] = *(const short8*)(&sX[buf][(brow + ni * 16) * BK2 + quad * 8]);
    __builtin_amdgcn_s_setprio(1);
#pragma unroll
    for (int mi = 0; mi < 4; ++mi)
#pragma unroll
      for (int ni = 0; ni < 4; ++ni)
        acc[mi][ni] = __builtin_amdgcn_mfma_f32_16x16x32_bf16(af[mi], bf[ni], acc[mi][ni], 0, 0, 0);
    __builtin_amdgcn_s_setprio(0);
    __syncthreads();  // drains DMA(kc+1); all waves done reading buf
  }

  // --- epilogue: C/D layout col=lane&15, row=quad*4+r (verbatim from proven kernel) ---
  float* outb = out + (b * OF + mt * BM) * Ln + pbase;
  int col = lane & 15;
#pragma unroll
  for (int mi = 0; mi < 4; ++mi) {
    int ob = (wave >> 1) * 64 + mi * 16 + quad * 4;
#pragma unroll
    for (int ni = 0; ni < 4; ++ni) {
      int p = (wave & 1) * 64 + ni * 16 + col;
#pragma unroll
      for (int r = 0; r < 4; ++r) outb[(ob + r) * Ln + p] = acc[mi][ni][r];
    }
  }
}

// ---------------- Fallback GEMM (round-0, proven 77us): used if ws too small ----------------
__global__ __launch_bounds__(256, 3) void gemm_fb(const float* __restrict__ X,
                                                  const unsigned short* __restrict__ Wm,
                                                  float* __restrict__ out) {
  __shared__ unsigned short sAf[2][BM * BK];
  __shared__ unsigned short sXf[BN * LDX];

  int flat = blockIdx.x;
  int logical = (flat & 7) * 192 + (flat >> 3);
  int mt = logical % 3;
  int nt = (logical / 3) & 31;
  int b = logical / 96;

  int t = threadIdx.x;
  int wave = t >> 6, lane = t & 63;
  int quad = lane >> 4;

  const float* Xb = X + b * (KF * Ln);
  const unsigned short* Wb = Wm + (b * OF + mt * BM) * KF;
  int pbase = nt * BN;

  floatx4 acc[4][4] = {};

  int i31 = t & 31;
  int p0 = i31 * 4;
  int kr0 = (t >> 5) * 8;
  int kr0s = (((t >> 5) ^ (i31 & 7)) * 8);
  int arow = (wave >> 1) * 64 + (lane & 15);
  int brow = (wave & 1) * 64 + (lane & 15);
  int asw = lane & 7;
  int xsw = ((lane & 15) >> 2);

  int aoff[4], asrc_row[4], asrc_c[4];
#pragma unroll
  for (int j = 0; j < 4; ++j) {
    int boff = wave * 4096 + j * 1024 + lane * 16;
    int row = boff >> 7;
    int cp = (boff >> 4) & 7;
    aoff[j] = boff;
    asrc_row[j] = row;
    asrc_c[j] = (cp ^ (row & 7)) * 8;
  }

  f32x4 xv[8];
  unsigned int wv4[4][4];

#pragma unroll
  for (int j = 0; j < 4; ++j)
    gl_lds16(Wb + asrc_row[j] * KF + 0 + asrc_c[j], (char*)sAf[0] + aoff[j]);
  {
    const float* xs = Xb + (0 + kr0) * Ln + pbase + p0;
#pragma unroll
    for (int i = 0; i < 8; ++i) xv[i] = *(const f32x4*)(xs + i * Ln);
#pragma unroll
    for (int j = 0; j < 4; ++j)
#pragma unroll
      for (int i = 0; i < 4; ++i)
        wv4[j][i] = pack2bf(xv[2 * i][j], xv[2 * i + 1][j]);
#pragma unroll
    for (int j = 0; j < 4; ++j)
      *(uint4v*)(&sXf[(p0 + j) * LDX + kr0s]) = *(uint4v*)wv4[j];
  }
  __syncthreads();

#pragma unroll
  for (int kc = 0; kc < 6; ++kc) {
    int cur = kc & 1;
    if (kc < 5) {
      int k0n = (kc + 1) * BK;
#pragma unroll
      for (int j = 0; j < 4; ++j)
        gl_lds16(Wb + asrc_row[j] * KF + k0n + asrc_c[j], (char*)sAf[cur ^ 1] + aoff[j]);
      const float* xs = Xb + (k0n + kr0) * Ln + pbase + p0;
#pragma unroll
      for (int i = 0; i < 8; ++i) xv[i] = *(const f32x4*)(xs + i * Ln);
    }
#pragma unroll
    for (int s = 0; s < 2; ++s) {
      short8 af[4], bf[4];
#pragma unroll
      for (int mi = 0; mi < 4; ++mi) {
        int ca = (((s << 2) | quad) ^ asw) * 8;
        af[mi] = *(const short8*)(&sAf[cur][(arow + mi * 16) * BK + ca]);
      }
#pragma unroll
      for (int ni = 0; ni < 4; ++ni) {
        int cx = (((s << 2) | quad) ^ (((ni & 1) << 2) | xsw)) * 8;
        bf[ni] = *(const short8*)(&sXf[(brow + ni * 16) * LDX + cx]);
      }
#pragma unroll
      for (int mi = 0; mi < 4; ++mi)
#pragma unroll
        for (int ni = 0; ni < 4; ++ni)
          acc[mi][ni] = __builtin_amdgcn_mfma_f32_16x16x32_bf16(af[mi], bf[ni], acc[mi][ni], 0, 0, 0);
    }
    if (kc < 5) {
#pragma unroll
      for (int j = 0; j < 4; ++j)
#pragma unroll
        for (int i = 0; i < 4; ++i)
          wv4[j][i] = pack2bf(xv[2 * i][j], xv[2 * i + 1][j]);
      __syncthreads();
#pragma unroll
      for (int j = 0; j < 4; ++j)
        *(uint4v*)(&sXf[(p0 + j) * LDX + kr0s]) = *(uint4v*)wv4[j];
      __syncthreads();
    }
  }

  float* outb = out + (b * OF + mt * BM) * Ln + pbase;
  int col = lane & 15;
#pragma unroll
  for (int mi = 0; mi < 4; ++mi) {
    int ob = (wave >> 1) * 64 + mi * 16 + quad * 4;
#pragma unroll
    for (int ni = 0; ni < 4; ++ni) {
      int p = (wave & 1) * 64 + ni * 16 + col;
#pragma unroll
      for (int r = 0; r < 4; ++r) outb[(ob + r) * Ln + p] = acc[mi][ni][r];
    }
  }
}

extern "C" void kernel_launch(void* const* d_in, const int* in_sizes, int n_in,
                              void* d_out, int out_size, void* d_ws, size_t ws_size,
                              hipStream_t stream) {
  const float* Efou = (const float*)d_in[0];    // [B, L, IN_F] fp32
  const float* y = (const float*)d_in[1];       // [B, IN_F] fp32
  const float* weight = (const float*)d_in[2];  // [1, OUT_F, IN_F] fp32
  float* out = (float*)d_out;                   // [B*OUT_F*L] fp32 (flat)
  unsigned short* wmod = (unsigned short*)d_ws; // [B, OUT_F, IN_F] bf16, 4.7MB

  const size_t wmod_elems = (size_t)Bn * OF * KF;                 // 2,359,296
  const size_t xbf_elems = (size_t)Bn * NKC * Ln * BK2;           // 25,165,824
  const size_t need_bytes = (wmod_elems + xbf_elems) * 2;         // 55,050,240

  modw_kernel<<<(Bn * OF) / 4, 256, 0, stream>>>(weight, y, wmod);
  if (ws_size >= need_bytes) {
    unsigned short* Xbf = wmod + wmod_elems;  // 16B-aligned (offset 4,718,592 B)
    xpose_kernel<<<(Bn * NKC * (Ln / 64)) / 4, 256, 0, stream>>>(Efou, Xbf);
    gemm_dma<<<Bn * (OF / BM) * (Ln / BN), 256, 0, stream>>>(Xbf, wmod, out);
  } else {
    gemm_fb<<<Bn * (OF / BM) * (Ln / BN), 256, 0, stream>>>(Efou, wmod, out);
  }
}